// Round 8
// baseline (425.199 us; speedup 1.0000x reference)
//
#include <hip/hip_runtime.h>
#include <cstdint>
#include <cstddef>

// ---------------------------------------------------------------------------
// EfficientAttention, Q-folded pipeline (Round 8):
//   out = x @ (Wq @ Wfused[b]) + bias
// GEMM template: BM=BN=256, BK=64, 128B LDS rows, chunk=(ks*4+quad)^(lr&7)
// 16x16x32 MFMA with lr/quad addressing — the EXACT read pattern measured at
// ZERO bank conflicts (R4 / bench round 2).  8 waves 2Mx4N, per-wave 128x64
// (8m x 4n frags, 24 ds_read / 64 MFMA per K-tile).  dbuf-2 (128 KiB) with
// half-tile staging: ph1 stages A(t+1) (other dbuf, A(t-1) dead), ph4 stages
// B(t+2) (own dbuf, B(t) fully read by ph3).  Counted vmcnt(4) once per tile
// (8-12 loads in flight, never drained mid-loop).  4 phases/tile x 16 MFMA,
// setprio(1) around clusters, lgkmcnt(0) after each barrier.
// ---------------------------------------------------------------------------

typedef __bf16 bf8_t __attribute__((ext_vector_type(8)));
typedef float f4_t __attribute__((ext_vector_type(4)));

#define DEV_INLINE __device__ __forceinline__

DEV_INLINE void gload16(const void* g, void* l) {
  __builtin_amdgcn_global_load_lds(
      (const __attribute__((address_space(1))) void*)g,
      (__attribute__((address_space(3))) void*)l, 16, 0, 0);
}

// ---------------- K0a: cast x (fp32) -> bf16, 4 elems/thread ----------------
__global__ __launch_bounds__(256) void cast_f32_bf16(const float* __restrict__ in,
                                                     __bf16* __restrict__ out, int n4) {
  int i = blockIdx.x * 256 + threadIdx.x;
  if (i >= n4) return;
  float4 f = ((const float4*)in)[i];
  union { __bf16 h[4]; uint2 u; } o;
  o.h[0] = (__bf16)f.x; o.h[1] = (__bf16)f.y; o.h[2] = (__bf16)f.z; o.h[3] = (__bf16)f.w;
  ((uint2*)out)[i] = o.u;
}

// ---------- K0b: tiled transpose: out[c*R + r] = (bf16) in[r*C + c] ---------
__global__ __launch_bounds__(256) void transpose_cast(const float* __restrict__ in,
                                                      __bf16* __restrict__ out, int R, int C) {
  __shared__ float t[64][65];
  const int tilesR = R >> 6;
  const int tr = blockIdx.x % tilesR, tc = blockIdx.x / tilesR;
  const int tx = threadIdx.x & 63, ty = threadIdx.x >> 6;
  const int r0 = tr * 64, c0 = tc * 64;
#pragma unroll
  for (int p = 0; p < 16; p++) {
    int r = p * 4 + ty;
    t[r][tx] = in[(size_t)(r0 + r) * C + c0 + tx];
  }
  __syncthreads();
#pragma unroll
  for (int p = 0; p < 16; p++) {
    int c = p * 4 + ty;
    out[(size_t)(c0 + c) * R + r0 + tx] = (__bf16)t[tx][c];
  }
}

// ---- K0c: Wq_cast[r][k] = (bf16) Wqkv[r][k], k<768 (strided row cast) ------
__global__ __launch_bounds__(256) void wq_cast(const float* __restrict__ in,
                                               __bf16* __restrict__ out) {
  int o = blockIdx.x * 256 + threadIdx.x;   // o in [0, 768*768)
  int r = o / 768, c = o - r * 768;
  out[o] = (__bf16)in[r * 2304 + c];
}

// ---------------------------------------------------------------------------
// GEMM template macros (BM=BN=256, BK=64, 512 thr = 8 waves 2Mx4N).
//   LDS: sA/sB each 2 dbuf x 256 rows x 64 bf16 (128B rows) = 64 KiB; 128 tot.
//   Store: 16B chunk c of row r at slot c ^ (r&7); staging pre-swizzles the
//   GLOBAL column (linear LDS dest).  Read (16x16x32 frag, k-slice ks):
//   row = base + m*16 + lr, chunk = (ks*4+quad) ^ (lr&7) — R4 pattern,
//   measured 0 conflicts.
// ---------------------------------------------------------------------------

#define MFMA16(aa, bb, cc) cc = __builtin_amdgcn_mfma_f32_16x16x32_bf16(aa, bb, cc, 0, 0, 0)

// Stage one half-tile (128 rows x 128B = 16 KiB): 2 gload16 per thread.
#define SA2(d, h, kc) do {                                                    \
    gload16(gAt + (size_t)((h) * 128) * 768 + (kc),                           \
            sA + (d) * 16384 + (h) * 8192 + tid * 8);                         \
    gload16(gAt + (size_t)((h) * 128 + 64) * 768 + (kc),                      \
            sA + (d) * 16384 + (h) * 8192 + 4096 + tid * 8);                  \
  } while (0)
#define SB2(d, h, kc) do {                                                    \
    gload16(gBt + (size_t)((h) * 128) * 768 + (kc),                           \
            sB + (d) * 16384 + (h) * 8192 + tid * 8);                         \
    gload16(gBt + (size_t)((h) * 128 + 64) * 768 + (kc),                      \
            sB + (d) * 16384 + (h) * 8192 + 4096 + tid * 8);                  \
  } while (0)
#define SA_ALL(d, kc) do { SA2(d, 0, kc); SA2(d, 1, kc); } while (0)
#define SB_ALL(d, kc) do { SB2(d, 0, kc); SB2(d, 1, kc); } while (0)

#define G_SETUP()                                                             \
  const int tid = threadIdx.x;                                                \
  const int srow0 = tid >> 3;                                                 \
  const int gc0 = ((tid & 7) ^ (srow0 & 7)) * 8;                              \
  const int lane = tid & 63, wv = tid >> 6;                                   \
  const int wm = wv >> 2, wn = wv & 3;                                        \
  const int lr = lane & 15, quad = lane >> 4, key = lr & 7;                   \
  const int kofs0 = (quad ^ key) * 8;        /* ks=0: chunk quad   */         \
  const int kofs1 = ((4 | quad) ^ key) * 8;  /* ks=1: chunk 4+quad */         \
  f4_t acc[8][4];                                                             \
  _Pragma("unroll") for (int i_ = 0; i_ < 8; i_++)                            \
    _Pragma("unroll") for (int j_ = 0; j_ < 4; j_++)                          \
      acc[i_][j_] = (f4_t){0.f, 0.f, 0.f, 0.f};

#define MROW(ai, mm)                                                          \
  MFMA16(ai, b0, acc[mm][0]); MFMA16(ai, b1, acc[mm][1]);                     \
  MFMA16(ai, b2, acc[mm][2]); MFMA16(ai, b3, acc[mm][3]);

// One K-tile (BK=64) = 4 phases x 16 MFMA.
//   ph1: reads A m0-3 ks0 + B n0-3 ks0; STG1 (= SA_ALL of tile t+1).
//   ph2: reads A m4-7 ks0 (B held in regs).
//   ph3: reads A m0-3 ks1 + B n0-3 ks1.
//   ph4: reads A m4-7 ks1; STG4 (= SB_ALL of tile t+2); TAILV (vmcnt).
#define G_TILE(d, STG1, STG4, TAILV) do {                                     \
    const __bf16* aB = sA + (d) * 16384 + wm * 8192 + lr * 64;                \
    const __bf16* bB = sB + (d) * 16384 + (wn >> 1) * 8192 +                  \
                       (wn & 1) * 4096 + lr * 64;                             \
    bf8_t a0, a1, a2, a3, b0, b1, b2, b3;                                     \
    a0 = *(const bf8_t*)(aB +        kofs0);                                  \
    a1 = *(const bf8_t*)(aB + 1024 + kofs0);                                  \
    a2 = *(const bf8_t*)(aB + 2048 + kofs0);                                  \
    a3 = *(const bf8_t*)(aB + 3072 + kofs0);                                  \
    b0 = *(const bf8_t*)(bB +        kofs0);                                  \
    b1 = *(const bf8_t*)(bB + 1024 + kofs0);                                  \
    b2 = *(const bf8_t*)(bB + 2048 + kofs0);                                  \
    b3 = *(const bf8_t*)(bB + 3072 + kofs0);                                  \
    STG1;                                                                     \
    __builtin_amdgcn_s_barrier();                                             \
    asm volatile("s_waitcnt lgkmcnt(0)" ::: "memory");                        \
    __builtin_amdgcn_s_setprio(1);                                            \
    MROW(a0, 0) MROW(a1, 1) MROW(a2, 2) MROW(a3, 3)                           \
    __builtin_amdgcn_s_setprio(0);                                            \
    __builtin_amdgcn_s_barrier();                                             \
    a0 = *(const bf8_t*)(aB + 4096 + kofs0);                                  \
    a1 = *(const bf8_t*)(aB + 5120 + kofs0);                                  \
    a2 = *(const bf8_t*)(aB + 6144 + kofs0);                                  \
    a3 = *(const bf8_t*)(aB + 7168 + kofs0);                                  \
    __builtin_amdgcn_s_barrier();                                             \
    asm volatile("s_waitcnt lgkmcnt(0)" ::: "memory");                        \
    __builtin_amdgcn_s_setprio(1);                                            \
    MROW(a0, 4) MROW(a1, 5) MROW(a2, 6) MROW(a3, 7)                           \
    __builtin_amdgcn_s_setprio(0);                                            \
    __builtin_amdgcn_s_barrier();                                             \
    a0 = *(const bf8_t*)(aB +        kofs1);                                  \
    a1 = *(const bf8_t*)(aB + 1024 + kofs1);                                  \
    a2 = *(const bf8_t*)(aB + 2048 + kofs1);                                  \
    a3 = *(const bf8_t*)(aB + 3072 + kofs1);                                  \
    b0 = *(const bf8_t*)(bB +        kofs1);                                  \
    b1 = *(const bf8_t*)(bB + 1024 + kofs1);                                  \
    b2 = *(const bf8_t*)(bB + 2048 + kofs1);                                  \
    b3 = *(const bf8_t*)(bB + 3072 + kofs1);                                  \
    __builtin_amdgcn_s_barrier();                                             \
    asm volatile("s_waitcnt lgkmcnt(0)" ::: "memory");                        \
    __builtin_amdgcn_s_setprio(1);                                            \
    MROW(a0, 0) MROW(a1, 1) MROW(a2, 2) MROW(a3, 3)                           \
    __builtin_amdgcn_s_setprio(0);                                            \
    __builtin_amdgcn_s_barrier();                                             \
    a0 = *(const bf8_t*)(aB + 4096 + kofs1);                                  \
    a1 = *(const bf8_t*)(aB + 5120 + kofs1);                                  \
    a2 = *(const bf8_t*)(aB + 6144 + kofs1);                                  \
    a3 = *(const bf8_t*)(aB + 7168 + kofs1);                                  \
    STG4;                                                                     \
    __builtin_amdgcn_s_barrier();                                             \
    asm volatile("s_waitcnt lgkmcnt(0)" ::: "memory");                        \
    __builtin_amdgcn_s_setprio(1);                                            \
    MROW(a0, 4) MROW(a1, 5) MROW(a2, 6) MROW(a3, 7)                           \
    __builtin_amdgcn_s_setprio(0);                                            \
    TAILV;                                                                    \
    __builtin_amdgcn_s_barrier();                                             \
  } while (0)

// K = 768 = 12 tiles of BK=64; dbuf by tile parity.
// Prologue: A(0), B(0), B(1); vmcnt(4) -> tile 0 landed, B(1) in flight.
// Loop t=0..9: ph1 stages A(t+1) (dbuf (t+1)&1; A(t-1) dead), ph4 stages
// B(t+2) (dbuf t&1; B(t) fully read at ph3), tail vmcnt(4) (forces B(t+1),
// A(t+1) landed; leaves B(t+2) in flight).  t=10: ph1 stages A(11), tail
// vmcnt(0) (drains A(11),B(11)).  t=11: pure compute.
#define G_MAIN() do {                                                         \
    SA_ALL(0, 0); SB_ALL(0, 0); SB_ALL(1, 64);                                \
    asm volatile("s_waitcnt vmcnt(4)" ::: "memory");                          \
    __builtin_amdgcn_s_barrier();                                             \
    for (int t = 0; t < 10; ++t) {                                            \
      const int d = t & 1;                                                    \
      const int kA = (t + 1) * 64, kB = (t + 2) * 64;                         \
      G_TILE(d, { SA_ALL(d ^ 1, kA); }, { SB_ALL(d, kB); },                   \
             { asm volatile("s_waitcnt vmcnt(4)" ::: "memory"); });           \
    }                                                                         \
    G_TILE(0, { SA_ALL(1, 704); }, {},                                        \
           { asm volatile("s_waitcnt vmcnt(0)" ::: "memory"); });             \
    G_TILE(1, {}, {}, {});                                                    \
  } while (0)

// ---------------- K1: GEMM1 kv = Xb @ Wqkv[:,768:] --------------------------
// A [32768,768] bf16 RM, B^T = WqkvT rows 768..2303 [1536,768] bf16 RM.
// grid 768 = 128 mt x 6 nt; XCD swizzle: 16 mt per XCD (A-tile L2 reuse).
__global__ __launch_bounds__(512, 2) void gemm1_kv(const __bf16* __restrict__ A,
                                                   const __bf16* __restrict__ B,
                                                   __bf16* __restrict__ KTo,
                                                   __bf16* __restrict__ VTo) {
  __shared__ __bf16 sA[2 * 16384];   // 2 x [256][64], 64 KiB
  __shared__ __bf16 sB[2 * 16384];   // 2 x [256][64], 64 KiB
  const int xcd = blockIdx.x & 7, g = blockIdx.x >> 3;
  const int mt = xcd * 16 + g / 6, nt = g % 6;
  G_SETUP();
  const __bf16* gAt = A + (size_t)(mt * 256 + srow0) * 768 + gc0;
  const __bf16* gBt = B + (size_t)(nt * 256 + srow0) * 768 + gc0;

  G_MAIN();

  // epilogue: C row = token, col in [0,1536): nt<3 -> K, nt>=3 -> V.
  // 16x16 C/D layout: col = lane&15, row = quad*4 + reg.
  const int sKV = (nt >= 3);
  __bf16* T = sKV ? VTo : KTo;
  const int bb = mt >> 4;                          // 16 m-tiles per batch
  const int tok0 = (mt & 15) * 256 + wm * 128 + quad * 4;
  const int cbase = (nt - sKV * 3) * 256 + wn * 64;
#pragma unroll
  for (int n = 0; n < 4; n++) {
    int c = cbase + n * 16 + lr;
    __bf16* Tp = T + ((size_t)(bb * 12 + (c >> 6)) * 64 + (c & 63)) * 4096;
#pragma unroll
    for (int m = 0; m < 8; m++) {
      union { __bf16 h4[4]; uint2 u2; } pk;
#pragma unroll
      for (int r = 0; r < 4; r++) pk.h4[r] = (__bf16)acc[m][n][r];
      *(uint2*)&Tp[tok0 + m * 16] = pk.u2;
    }
  }
}

// ------ K3: row stats (max, 1/sumexp) per KT row; NO writeback --------------
__global__ __launch_bounds__(256) void stats_rows(const __bf16* __restrict__ KT,
                                                  float2* __restrict__ stats) {
  __shared__ float red[8];
  const __bf16* p = KT + (size_t)blockIdx.x * 4096;
  const int tid = threadIdx.x, lane = tid & 63, wv = tid >> 6;
  bf8_t x0 = *(const bf8_t*)&p[tid * 16];
  bf8_t x1 = *(const bf8_t*)&p[tid * 16 + 8];
  float v[16];
#pragma unroll
  for (int k = 0; k < 8; k++) { v[k] = (float)x0[k]; v[8 + k] = (float)x1[k]; }
  float m = v[0];
#pragma unroll
  for (int k = 1; k < 16; k++) m = fmaxf(m, v[k]);
  for (int o = 32; o; o >>= 1) m = fmaxf(m, __shfl_xor(m, o, 64));
  if (lane == 0) red[wv] = m;
  __syncthreads();
  m = fmaxf(fmaxf(red[0], red[1]), fmaxf(red[2], red[3]));
  float s = 0.f;
#pragma unroll
  for (int k = 0; k < 16; k++) s += __expf(v[k] - m);
  for (int o = 32; o; o >>= 1) s += __shfl_xor(s, o, 64);
  if (lane == 0) red[4 + wv] = s;
  __syncthreads();
  if (tid == 0) {
    float st = red[4] + red[5] + red[6] + red[7];
    stats[blockIdx.x] = make_float2(m, 1.0f / st);
  }
}

// --------- K4: ctx partials with inline exp. grid = 96*8 --------------------
__global__ __launch_bounds__(256) void ctx_kernel(const __bf16* __restrict__ KT,
                                                  const __bf16* __restrict__ VT,
                                                  const float2* __restrict__ stats,
                                                  float* __restrict__ part) {
  const int bh = blockIdx.x >> 3, kc = blockIdx.x & 7;
  const int tid = threadIdx.x, lane = tid & 63, wv = tid >> 6;
  const int wr = (wv >> 1) * 32, wc = (wv & 1) * 32;
  const int lr = lane & 15, quad = lane >> 4;
  const __bf16* Ab = KT + (size_t)bh * 64 * 4096;
  const __bf16* Bb = VT + (size_t)bh * 64 * 4096;
  float2 st[2];
  st[0] = stats[bh * 64 + wr + lr];
  st[1] = stats[bh * 64 + wr + 16 + lr];
  const f4_t fz = {0.f, 0.f, 0.f, 0.f};
  f4_t acc[2][2] = {{fz, fz}, {fz, fz}};
  const int kbeg = kc * 512;
  for (int k0 = kbeg; k0 < kbeg + 512; k0 += 32) {
    bf8_t a[2], b[2];
#pragma unroll
    for (int i = 0; i < 2; i++) {
      bf8_t raw = *(const bf8_t*)&Ab[(size_t)(wr + i * 16 + lr) * 4096 + k0 + quad * 8];
#pragma unroll
      for (int e = 0; e < 8; e++)
        a[i][e] = (__bf16)(__expf((float)raw[e] - st[i].x) * st[i].y);
    }
#pragma unroll
    for (int j = 0; j < 2; j++)
      b[j] = *(const bf8_t*)&Bb[(size_t)(wc + j * 16 + lr) * 4096 + k0 + quad * 8];
#pragma unroll
    for (int i = 0; i < 2; i++)
#pragma unroll
      for (int j = 0; j < 2; j++)
        acc[i][j] = __builtin_amdgcn_mfma_f32_16x16x32_bf16(a[i], b[j], acc[i][j], 0, 0, 0);
  }
  float* po = part + (size_t)blockIdx.x * 4096;
#pragma unroll
  for (int i = 0; i < 2; i++)
#pragma unroll
    for (int j = 0; j < 2; j++)
#pragma unroll
      for (int r = 0; r < 4; r++)
        po[(wr + i * 16 + quad * 4 + r) * 64 + wc + j * 16 + lr] = acc[i][j][r];
}

// -------- K5: B2T[b][c][h*64+d] = sum_e ctx[bh][d][e] * Wproj[h*64+e][c] ----
__global__ __launch_bounds__(256) void wfused_kernel(const float* __restrict__ part,
                                                     const __bf16* __restrict__ WpT,
                                                     __bf16* __restrict__ B2T) {
  __shared__ __bf16 sctx[64 * 64];
  const int bh = blockIdx.x, cblk = blockIdx.y;
  const int b = bh / 12, h = bh % 12;
  const int tid = threadIdx.x;
  for (int i = tid; i < 4096; i += 256) {
    float s = 0.f;
#pragma unroll
    for (int kc = 0; kc < 8; kc++) s += part[(size_t)(bh * 8 + kc) * 4096 + i];
    sctx[i] = (__bf16)s;
  }
  __syncthreads();
  const int lane = tid & 63, wv = tid >> 6, lr = lane & 15, quad = lane >> 4;
  const int c0 = cblk * 192 + wv * 48;
  const f4_t fz = {0.f, 0.f, 0.f, 0.f};
  f4_t acc[3][4];
#pragma unroll
  for (int i = 0; i < 3; i++)
#pragma unroll
    for (int j = 0; j < 4; j++) acc[i][j] = fz;
#pragma unroll
  for (int k0 = 0; k0 < 64; k0 += 32) {
    bf8_t a[3], bq[4];
#pragma unroll
    for (int i = 0; i < 3; i++)
      a[i] = *(const bf8_t*)&WpT[(size_t)(c0 + i * 16 + lr) * 768 + h * 64 + k0 + quad * 8];
#pragma unroll
    for (int j = 0; j < 4; j++)
      bq[j] = *(const bf8_t*)&sctx[(j * 16 + lr) * 64 + k0 + quad * 8];
#pragma unroll
    for (int i = 0; i < 3; i++)
#pragma unroll
      for (int j = 0; j < 4; j++)
        acc[i][j] = __builtin_amdgcn_mfma_f32_16x16x32_bf16(a[i], bq[j], acc[i][j], 0, 0, 0);
  }
#pragma unroll
  for (int i = 0; i < 3; i++)
#pragma unroll
    for (int j = 0; j < 4; j++)
#pragma unroll
      for (int r = 0; r < 4; r++) {
        int c = c0 + i * 16 + quad * 4 + r;
        int d = j * 16 + lr;
        B2T[((size_t)b * 768 + c) * 768 + h * 64 + d] = (__bf16)acc[i][j][r];
      }
}

// ------ K5b: combine  Wcomb^T[b][c_out][c_in] = sum_k B2T[b][c_out][k]*Wq[c_in][k]
__global__ __launch_bounds__(256) void combine_kernel(const __bf16* __restrict__ B2Tall,
                                                      const __bf16* __restrict__ Wq,
                                                      __bf16* __restrict__ Wcomb) {
  constexpr int LD = 768, BK = 32, KTOT = 768;
  __shared__ __bf16 sAc[64 * 32];
  __shared__ __bf16 sBc[64 * 32];
  const int b = blockIdx.x / 144, rem = blockIdx.x % 144;
  const int mt = rem / 12, nt = rem % 12;
  const __bf16* A = B2Tall + (size_t)b * 768 * 768;
  const int tid = threadIdx.x, lane = tid & 63, wv = tid >> 6;
  const int wr = (wv >> 1) * 32, wc = (wv & 1) * 32;
  const int lr = lane & 15, quad = lane >> 4;

  const int e0 = tid * 8;
  const int srow = e0 >> 5, skk = e0 & 31;
  const __bf16* gA = A + (size_t)(mt * 64 + srow) * LD + skk;
  const __bf16* gB = Wq + (size_t)(nt * 64 + srow) * LD + skk;

  const f4_t fz = {0.f, 0.f, 0.f, 0.f};
  f4_t acc[2][2] = {{fz, fz}, {fz, fz}};

  for (int k0 = 0; k0 < KTOT; k0 += BK) {
    gload16(gA, &sAc[e0]);
    gload16(gB, &sBc[e0]);
    gA += BK; gB += BK;
    __syncthreads();
    bf8_t a[2], bq[2];
#pragma unroll
    for (int i = 0; i < 2; i++)
      a[i] = *(const bf8_t*)&sAc[(wr + i * 16 + lr) * 32 + quad * 8];
#pragma unroll
    for (int j = 0; j < 2; j++)
      bq[j] = *(const bf8_t*)&sBc[(wc + j * 16 + lr) * 32 + quad * 8];
#pragma unroll
    for (int i = 0; i < 2; i++)
#pragma unroll
      for (int j = 0; j < 2; j++)
        acc[i][j] = __builtin_amdgcn_mfma_f32_16x16x32_bf16(a[i], bq[j], acc[i][j], 0, 0, 0);
    __syncthreads();
  }
  __bf16* C = Wcomb + (size_t)b * 768 * 768;
  const int row0 = mt * 64 + wr, col0 = nt * 64 + wc;
#pragma unroll
  for (int i = 0; i < 2; i++)
#pragma unroll
    for (int j = 0; j < 2; j++)
#pragma unroll
      for (int r = 0; r < 4; r++)
        C[(size_t)(row0 + i * 16 + quad * 4 + r) * 768 + col0 + j * 16 + lr] =
            (__bf16)acc[i][j][r];
}

// ------------- K6: GEMM2 out = Xb @ Wcomb^T[b] + bproj ----------------------
// grid 384 = 128 mt x 3 nt; XCD swizzle: each XCD owns one batch -> Wcomb
// (1.2 MB) L2-resident.
__global__ __launch_bounds__(512, 2) void gemm2_out(const __bf16* __restrict__ A,
                                                    const __bf16* __restrict__ Ball,
                                                    float* __restrict__ C,
                                                    const float* __restrict__ bias) {
  __shared__ __bf16 sA[2 * 16384];
  __shared__ __bf16 sB[2 * 16384];
  const int xcd = blockIdx.x & 7, g = blockIdx.x >> 3;
  const int mt = xcd * 16 + g / 3, nt = g % 3;
  const __bf16* B = Ball + (size_t)(mt >> 4) * 768 * 768;
  G_SETUP();
  const __bf16* gAt = A + (size_t)(mt * 256 + srow0) * 768 + gc0;
  const __bf16* gBt = B + (size_t)(nt * 256 + srow0) * 768 + gc0;

  G_MAIN();

  const int row0 = mt * 256 + wm * 128 + quad * 4;
  const int col0 = nt * 256 + wn * 64;
#pragma unroll
  for (int n = 0; n < 4; n++) {
    int col = col0 + n * 16 + lr;
    float bv = bias[col];
#pragma unroll
    for (int m = 0; m < 8; m++) {
#pragma unroll
      for (int r = 0; r < 4; r++)
        C[(size_t)(row0 + m * 16 + r) * 768 + col] = acc[m][n][r] + bv;
    }
  }
}

// ---------------------------------------------------------------------------
extern "C" void kernel_launch(void* const* d_in, const int* in_sizes, int n_in,
                              void* d_out, int out_size, void* d_ws, size_t ws_size,
                              hipStream_t stream) {
  const float* x = (const float*)d_in[0];      // [8,4096,768]
  const float* Wqkv = (const float*)d_in[1];   // [768,2304]
  const float* Wproj = (const float*)d_in[2];  // [768,768]
  const float* bproj = (const float*)d_in[3];  // [768]
  float* out = (float*)d_out;                  // [8,4096,768]

  char* ws = (char*)d_ws;
  __bf16* Xb    = (__bf16*)(ws + 0);            // 50,331,648
  __bf16* KT    = (__bf16*)(ws + 50331648);     // 50,331,648
  __bf16* VT    = (__bf16*)(ws + 100663296);    // 50,331,648
  __bf16* WqkvT = (__bf16*)(ws + 150994944);    //  3,538,944 (dead after gemm1)
  float2* stats = (float2*)(ws + 150994944);    //  49,152 (aliases dead WqkvT)
  __bf16* Wqc   = (__bf16*)(ws + 154533888);    //  1,179,648
  __bf16* WpT   = (__bf16*)(ws + 155713536);    //  1,179,648
  float*  part  = (float*)(ws + 156893184);     // 12,582,912
  __bf16* B2T   = (__bf16*)(ws + 169476096);    //  9,437,184
  __bf16* Wcomb = (__bf16*)(ws + 178913280);    //  9,437,184 -> end 188,350,464

  cast_f32_bf16<<<24576, 256, 0, stream>>>(x, Xb, 25165824 / 4);
  transpose_cast<<<12 * 36, 256, 0, stream>>>(Wqkv, WqkvT, 768, 2304);
  wq_cast<<<(768 * 768) / 256, 256, 0, stream>>>(Wqkv, Wqc);
  transpose_cast<<<12 * 12, 256, 0, stream>>>(Wproj, WpT, 768, 768);
  gemm1_kv<<<768, 512, 0, stream>>>(Xb, WqkvT + 768 * 768, KT, VT);
  stats_rows<<<6144, 256, 0, stream>>>(KT, stats);
  ctx_kernel<<<96 * 8, 256, 0, stream>>>(KT, VT, stats, part);
  wfused_kernel<<<dim3(96, 4), 256, 0, stream>>>(part, WpT, B2T);
  combine_kernel<<<1152, 256, 0, stream>>>(B2T, Wqc, Wcomb);
  gemm2_out<<<384, 512, 0, stream>>>(Xb, Wcomb, out, bproj);
}